// Round 3
// baseline (515.239 us; speedup 1.0000x reference)
//
#include <hip/hip_runtime.h>
#include <hip/hip_bf16.h>
#include <stdint.h>

// Problem constants
#define NEXP   16
#define TTOK   32768
#define HIN    2048
#define RNK    128
#define OOUT   2048
#define BM     64              // tokens per block (64 -> 512 blocks -> 2 blocks/CU)
#define LORA_SCALE 0.25f       // alpha/rank = 32/128

typedef __bf16 bf16_t;
typedef bf16_t bf16x8 __attribute__((ext_vector_type(8)));
typedef bf16_t bf16x4 __attribute__((ext_vector_type(4)));
typedef float  f32x4  __attribute__((ext_vector_type(4)));

// Barrier WITHOUT vmcnt drain (T4): only LDS ops must be visible across the
// barrier. Global loads land in registers (compiler inserts counted vmcnt at
// each use); Out stores are never read. Keeping loads/stores in flight across
// barriers is the whole point of this round.
#define BARRIER() asm volatile("s_waitcnt lgkmcnt(0)\n\ts_barrier" ::: "memory")

// ---------------------------------------------------------------------------
// Per-expert transpose + fp32->bf16 convert: src f32 [E][Rr][Cc] -> dst bf16 [E][Cc][Rr]
// (unchanged from verified baseline)
// ---------------------------------------------------------------------------
__global__ void transpose_cvt_kernel(const float* __restrict__ src,
                                     bf16_t* __restrict__ dst,
                                     int Rr, int Cc)
{
    __shared__ float tile[32][33];
    const int e  = blockIdx.z;
    const int c0 = blockIdx.x * 32;
    const int r0 = blockIdx.y * 32;
    const float* s = src + (size_t)e * Rr * Cc;
    bf16_t*      d = dst + (size_t)e * Rr * Cc;
    const int tx = threadIdx.x & 31;
    const int ty = threadIdx.x >> 5;   // 0..7
#pragma unroll
    for (int j = 0; j < 32; j += 8)
        tile[ty + j][tx] = s[(size_t)(r0 + ty + j) * Cc + (c0 + tx)];
    __syncthreads();
#pragma unroll
    for (int j = 0; j < 32; j += 8)
        d[(size_t)(c0 + ty + j) * Rr + (r0 + tx)] = (bf16_t)tile[tx][ty + j];
}

// ---------------------------------------------------------------------------
// Fused grouped LoRA, 64-token blocks, 2 blocks/CU (LDS = 64 KB):
//   phase 1: L[64][128] = x_tile[64][2048] @ At[e]^T   (acc fp32, L -> bf16 LDS)
//   phase 2: out_tile[64][2048] = L @ Btw[e]^T * scale
// 512 threads = 8 waves (2m x 4c), wave tile 32x32.
// Swapped-operand MFMA (mfma(B,A)): lane&15 = output ROW, q*4+reg = output COL.
// All LDS tiles XOR-swizzled: byte ^= ((row&7)<<4)  (reg-staged both sides).
// Depth-2 register prefetch + non-draining barriers keep ~64 KB/block of
// global loads in flight continuously (Little's law for full HBM duty).
// LDS map, phase 1: Xs dbuf [0,16K), As dbuf [16K,48K), L [48K,64K).
//           phase 2: B dbuf  [0,32K)+[32K,64K)  (L dead after af2 reg-load).
// ---------------------------------------------------------------------------
__global__ __launch_bounds__(512, 4)
void fused_lora(const float* __restrict__ X,
                const bf16_t* __restrict__ Atw,
                const bf16_t* __restrict__ Btw,
                float* __restrict__ Out)
{
    __shared__ __align__(16) char lds[65536];

    const int tid = threadIdx.x;
    // XCD-chunked bijective swizzle (grid=512, 512%8==0): 64 consecutive
    // logical blocks per XCD -> each XCD touches 2 experts (L2-resident).
    const int bid = blockIdx.x;
    const int blk = (bid & 7) * 64 + (bid >> 3);
    const int m0  = blk * BM;
    const int e   = blk >> 5;             // 32 blocks per expert

    const int wave = tid >> 6;            // 0..7
    const int lane = tid & 63;
    const int lm   = lane & 15;
    const int q    = lane >> 4;
    const int wr   = (wave & 1) * 32;     // m offset: 0/32
    const int wc   = (wave >> 1) * 32;    // r (phase1) / n (phase2) offset

    // staging maps
    const int sxr = tid >> 3, sxc = tid & 7;   // X: 64 rows x 8 slots of 8 floats
    const int sar = tid >> 2, sac = tid & 3;   // A/B: 128 rows x 4 slots
    const int xsw = (sxr & 7) << 4;
    const int asw = (sar & 7) << 4;

    const float*  xg = X   + (size_t)(m0 + sxr) * HIN + sxc * 8;
    const bf16_t* ag = Atw + ((size_t)e * RNK + sar) * HIN + sac * 16;

    char* XsBase = lds;                  // 2 x 8 KB
    char* AsBase = lds + 16384;          // 2 x 16 KB
    char* Lb     = lds + 49152;          // 16 KB

    f32x4  xA0, xA1, xB0, xB1;           // two prefetch register sets
    bf16x8 aA0, aA1, aB0, aB1;
    f32x4  acc1[2][2] = {};

    // ---------------- phase 1: L = x @ A^T, K = 2048, BK = 64 ----------------
    // prologue: issue slab0 -> setA and slab1 -> setB, stage slab0 -> buf0
    xA0 = *(const f32x4*)(xg);        xA1 = *(const f32x4*)(xg + 4);
    aA0 = *(const bf16x8*)(ag);       aA1 = *(const bf16x8*)(ag + 8);
    xB0 = *(const f32x4*)(xg + 64);   xB1 = *(const f32x4*)(xg + 68);
    aB0 = *(const bf16x8*)(ag + 64);  aB1 = *(const bf16x8*)(ag + 72);
    {
        bf16x8 cx;
#pragma unroll
        for (int i = 0; i < 4; ++i) { cx[i] = (bf16_t)xA0[i]; cx[4 + i] = (bf16_t)xA1[i]; }
        *(bf16x8*)(XsBase + sxr * 128 + ((sxc * 16) ^ xsw)) = cx;
        *(bf16x8*)(AsBase + sar * 128 + ((sac * 32     ) ^ asw)) = aA0;
        *(bf16x8*)(AsBase + sar * 128 + ((sac * 32 + 16) ^ asw)) = aA1;
    }
    BARRIER();

    // step: at iter it -- reload set L gets slab it+2; stage set S (slab it+1)
    auto p1_step = [&](int it,
                       f32x4& lx0, f32x4& lx1, bf16x8& la0, bf16x8& la1,
                       f32x4& sx0, f32x4& sx1, bf16x8& sa0, bf16x8& sa1)
    {
        const int cur = it & 1;
        if (it < 30) {
            const float*  px = xg + (size_t)(it + 2) * 64;
            const bf16_t* pa = ag + (size_t)(it + 2) * 64;
            lx0 = *(const f32x4*)px;   lx1 = *(const f32x4*)(px + 4);
            la0 = *(const bf16x8*)pa;  la1 = *(const bf16x8*)(pa + 8);
        }
        const char* xb = XsBase + cur * 8192;
        const char* ab = AsBase + cur * 16384;
#pragma unroll
        for (int ks = 0; ks < 2; ++ks) {
            bf16x8 XF[2], AF[2];
#pragma unroll
            for (int mt = 0; mt < 2; ++mt) {
                const int row = wr + mt * 16 + lm;
                XF[mt] = *(const bf16x8*)(xb + row * 128 +
                           ((ks * 64 + q * 16) ^ ((row & 7) << 4)));
            }
#pragma unroll
            for (int ct = 0; ct < 2; ++ct) {
                const int row = wc + ct * 16 + lm;
                AF[ct] = *(const bf16x8*)(ab + row * 128 +
                           ((ks * 64 + q * 16) ^ ((row & 7) << 4)));
            }
#pragma unroll
            for (int mt = 0; mt < 2; ++mt)
#pragma unroll
                for (int ct = 0; ct < 2; ++ct)
                    acc1[mt][ct] = __builtin_amdgcn_mfma_f32_16x16x32_bf16(
                        AF[ct], XF[mt], acc1[mt][ct], 0, 0, 0);
        }
        if (it < 31) {
            bf16x8 cx;
#pragma unroll
            for (int i = 0; i < 4; ++i) { cx[i] = (bf16_t)sx0[i]; cx[4 + i] = (bf16_t)sx1[i]; }
            *(bf16x8*)(XsBase + (cur ^ 1) * 8192 + sxr * 128 + ((sxc * 16) ^ xsw)) = cx;
            *(bf16x8*)(AsBase + (cur ^ 1) * 16384 + sar * 128 + ((sac * 32     ) ^ asw)) = sa0;
            *(bf16x8*)(AsBase + (cur ^ 1) * 16384 + sar * 128 + ((sac * 32 + 16) ^ asw)) = sa1;
        }
        BARRIER();
    };

    for (int it2 = 0; it2 < 16; ++it2) {
        p1_step(2 * it2,     xA0, xA1, aA0, aA1,  xB0, xB1, aB0, aB1);
        p1_step(2 * it2 + 1, xB0, xB1, aB0, aB1,  xA0, xA1, aA0, aA1);
    }

    // ---------------- transition: issue B0/B1 loads, L -> LDS, af2 regs -----
    bf16x8 bA[4], bB[4];
    const bf16_t* bg0 = Btw + ((size_t)e * OOUT + sar) * RNK + sac * 32;
#pragma unroll
    for (int i = 0; i < 4; ++i) bA[i] = *(const bf16x8*)(bg0 + i * 8);
#pragma unroll
    for (int i = 0; i < 4; ++i) bB[i] = *(const bf16x8*)(bg0 + (size_t)128 * RNK + i * 8);

    // swapped-operand layout: lane holds L[m = wr+mt*16+lm][r = wc+ct*16+q*4+reg]
#pragma unroll
    for (int mt = 0; mt < 2; ++mt) {
        const int m   = wr + mt * 16 + lm;
        const int msw = (m & 7) << 4;
#pragma unroll
        for (int ct = 0; ct < 2; ++ct) {
            const int r0 = wc + ct * 16 + q * 4;
            bf16x4 v;
#pragma unroll
            for (int i = 0; i < 4; ++i) v[i] = (bf16_t)acc1[mt][ct][i];
            *(bf16x4*)(Lb + m * 256 + ((r0 * 2) ^ msw)) = v;
        }
    }
    BARRIER();   // L visible to all waves

    // A-operand fragments for phase 2: load ONCE, reuse for all 16 N-chunks
    bf16x8 af2[2][4];
#pragma unroll
    for (int mt = 0; mt < 2; ++mt) {
        const int m   = wr + mt * 16 + lm;
        const int msw = (m & 7) << 4;
#pragma unroll
        for (int ks = 0; ks < 4; ++ks)
            af2[mt][ks] = *(const bf16x8*)(Lb + m * 256 + ((ks * 64 + q * 16) ^ msw));
    }

    // stage B chunk 0 into buf 0 ([0,32K): phase-1 staging region, now dead)
    {
        char* bb = lds + sar * 256;
#pragma unroll
        for (int i = 0; i < 4; ++i)
            *(bf16x8*)(bb + ((sac * 64 + i * 16) ^ asw)) = bA[i];
    }
    BARRIER();   // chunk 0 staged; all af2 reads done (buf1/Lb may be overwritten)

    // ---------------- phase 2: out = L @ B^T * scale, 16 chunks of 128 cols --
    auto p2_step = [&](int c, bf16x8* lset, bf16x8* sset)
    {
        const int cur = c & 1;
        if (c < 14) {
            const bf16_t* bg = bg0 + (size_t)(c + 2) * 128 * RNK;
#pragma unroll
            for (int i = 0; i < 4; ++i) lset[i] = *(const bf16x8*)(bg + i * 8);
        }
        f32x4 acc2[2][2] = {};
        const char* bb = lds + cur * 32768;
#pragma unroll
        for (int nt = 0; nt < 2; ++nt) {
            const int n   = wc + nt * 16 + lm;
            const int nsw = (n & 7) << 4;
#pragma unroll
            for (int ks = 0; ks < 4; ++ks) {
                const bf16x8 BF = *(const bf16x8*)(bb + n * 256 +
                                     ((ks * 64 + q * 16) ^ nsw));
                acc2[0][nt] = __builtin_amdgcn_mfma_f32_16x16x32_bf16(
                    BF, af2[0][ks], acc2[0][nt], 0, 0, 0);
                acc2[1][nt] = __builtin_amdgcn_mfma_f32_16x16x32_bf16(
                    BF, af2[1][ks], acc2[1][nt], 0, 0, 0);
            }
        }
        // epilogue: lane holds out[m][n0..n0+4) -> f32x4 stores (fire-and-forget)
#pragma unroll
        for (int mt = 0; mt < 2; ++mt) {
            const int gm = m0 + wr + mt * 16 + lm;
            float* orow = Out + (size_t)gm * OOUT + c * 128 + wc + q * 4;
#pragma unroll
            for (int nt = 0; nt < 2; ++nt) {
                const f32x4 v = acc2[mt][nt] * LORA_SCALE;
                *(f32x4*)(orow + nt * 16) = v;
            }
        }
        if (c < 15) {
            char* bb2 = lds + (cur ^ 1) * 32768 + sar * 256;
#pragma unroll
            for (int i = 0; i < 4; ++i)
                *(bf16x8*)(bb2 + ((sac * 64 + i * 16) ^ asw)) = sset[i];
        }
        BARRIER();
    };

    for (int c2 = 0; c2 < 8; ++c2) {
        p2_step(2 * c2,     bA, bB);
        p2_step(2 * c2 + 1, bB, bA);
    }
}

// ---------------------------------------------------------------------------
extern "C" void kernel_launch(void* const* d_in, const int* in_sizes, int n_in,
                              void* d_out, int out_size, void* d_ws, size_t ws_size,
                              hipStream_t stream)
{
    const float* x  = (const float*)d_in[0];   // fp32 [TTOK, HIN]
    const float* la = (const float*)d_in[1];   // fp32 [E, HIN, RNK]
    const float* lb = (const float*)d_in[2];   // fp32 [E, RNK, OOUT]
    float* out = (float*)d_out;                // fp32 [TTOK, OOUT]

    // workspace layout:
    //   At  bf16 [E][RNK][HIN]   (8 MB)
    //   Btw bf16 [E][OOUT][RNK]  (8 MB)
    bf16_t* At  = (bf16_t*)d_ws;
    bf16_t* Btw = At + (size_t)NEXP * RNK * HIN;

    // transpose+convert lora_a: f32 [E][HIN][RNK] -> bf16 At [E][RNK][HIN]
    {
        dim3 g(RNK / 32, HIN / 32, NEXP);
        transpose_cvt_kernel<<<g, 256, 0, stream>>>(la, At, HIN, RNK);
    }
    // transpose+convert lora_b: f32 [E][RNK][OOUT] -> bf16 Btw [E][OOUT][RNK]
    {
        dim3 g(OOUT / 32, RNK / 32, NEXP);
        transpose_cvt_kernel<<<g, 256, 0, stream>>>(lb, Btw, RNK, OOUT);
    }
    // fused LoRA: 64 tokens per block, 512 blocks, 2 blocks/CU, 8 waves each
    fused_lora<<<dim3(TTOK / BM), dim3(512), 0, stream>>>(x, At, Btw, out);
}